// Round 1
// 246.393 us; speedup vs baseline: 1.0160x; 1.0160x over previous
//
#include <hip/hip_runtime.h>

typedef short bf16x8 __attribute__((ext_vector_type(8)));
typedef float f32x16 __attribute__((ext_vector_type(16)));

#define XROW 2176              // 34 xp * 64B per (z,y) LDS row
#define KF2_BYTES 442368       // 27648 * 16
#define XT_ROWS 8976           // 4b * 34pd * 66ph
#define XT_ROW_BYTES 4224      // 66 pw * 64B
#define XT_BYTES 37914624      // 8976 * 4224
#define WS_NEED (KF2_BYTES + XT_BYTES)

__device__ __forceinline__ unsigned short f2bf(float f) {
    unsigned u = __float_as_uint(f);
    return (unsigned short)((u + 0x7FFFu + ((u >> 16) & 1u)) >> 16);
}

// ---- prep: blocks [0,nxt) build the padded/swizzled bf16 xt tensor;
//            blocks [nxt, nxt+108) build keff (A-fragment order, unchanged layout).
// xt layout: row n = (b*34 + pd)*66 + ph holds 66 points (pw) of 64B each.
// Point pw stores channel-chunk q = pos ^ ((pw>>1)&3) at sub-slot pos (swizzle
// pre-baked; tile-independent since tile origins are multiples of 32 in w).
// Halo (d,h,w out of range) is zero-filled so conv needs NO bounds checks.
__global__ __launch_bounds__(256) void prep(const float* __restrict__ x,
                                            const float* __restrict__ stencils,
                                            const float* __restrict__ weight,
                                            uint4* __restrict__ kf2,
                                            uint4* __restrict__ xt,
                                            int nxt) {
    int tid = threadIdx.x;
    int blk = blockIdx.x;

    if (blk >= nxt) {
        // ---- keff: kf2[b][r][s][mt][lane]; lane chunk = keff[o][c..c+7],
        // o = (lane&31)+32*mt, c = s*16+(lane>>5)*8.
        int i = (blk - nxt) * 256 + tid;
        if (i >= 27648) return;
        int lane = i & 63;
        int mt = (i >> 6) & 1;
        int s  = (i >> 7) & 1;
        int br = i >> 8;
        int r = br % 27, b = br / 27;
        int o  = (lane & 31) + 32 * mt;
        int cb = s * 16 + (lane >> 5) * 8;
        float st[8];
        #pragma unroll
        for (int t = 0; t < 8; ++t) st[t] = stencils[((size_t)b * 8 + t) * 27 + r];
        unsigned short us[8];
        #pragma unroll
        for (int j = 0; j < 8; ++j) {
            const float* wp = weight + ((size_t)o * 32 + cb + j) * 8;
            float acc = 0.f;
            #pragma unroll
            for (int t = 0; t < 8; ++t) acc += wp[t] * st[t];
            us[j] = f2bf(acc);
        }
        uint4 v;
        v.x = us[0] | ((unsigned)us[1] << 16);
        v.y = us[2] | ((unsigned)us[3] << 16);
        v.z = us[4] | ((unsigned)us[5] << 16);
        v.w = us[6] | ((unsigned)us[7] << 16);
        kf2[i] = v;
        return;
    }

    // ---- xt row
    int n = blk;
    int ph = n % 66;
    int t2 = n / 66;
    int pd = t2 % 34, b = t2 / 34;
    uint4* rowp = xt + (size_t)n * 264;          // 66 pts * 4 uint4
    int d = pd - 1, h = ph - 1;

    if ((unsigned)d >= 32u || (unsigned)h >= 64u) {
        // halo row: all zeros (264 uint4)
        for (int i = tid; i < 264; i += 256) rowp[i] = make_uint4(0u, 0u, 0u, 0u);
        return;
    }

    // interior: wave q reads channels [8q,8q+8) fully coalesced (256B/instr)
    int q = tid >> 6, w = tid & 63;
    const float* xb = x + (((size_t)(b * 32 + q * 8) * 32 + d) * 64 + h) * 64 + w;
    unsigned short us[8];
    #pragma unroll
    for (int j = 0; j < 8; ++j) us[j] = f2bf(xb[(size_t)j * 131072]);
    uint4 v;
    v.x = us[0] | ((unsigned)us[1] << 16);
    v.y = us[2] | ((unsigned)us[3] << 16);
    v.z = us[4] | ((unsigned)us[5] << 16);
    v.w = us[6] | ((unsigned)us[7] << 16);
    int pw = w + 1;
    int pos = q ^ ((pw >> 1) & 3);
    rowp[pw * 4 + pos] = v;
    // w-pad points: pw=0 (slots 0-3) and pw=65 (slots 0-3 at 260..263 = 256+tid)
    if (tid < 4)      rowp[tid]       = make_uint4(0u, 0u, 0u, 0u);
    else if (tid < 8) rowp[256 + tid] = make_uint4(0u, 0u, 0u, 0u);
}

// ---- conv: block = 64 couts x (2d x 4h x 32w). Prologue is now a pure DMA:
// 13 unconditional global_load_lds dwordx4 per thread (contiguous 2176B/row,
// swizzle pre-baked in xt, halo pre-zeroed). K-loop/epilogue unchanged.
__global__ __launch_bounds__(256, 3) void conv_fused(
    const uint4* __restrict__ xt, const uint4* __restrict__ kf2,
    const float* __restrict__ bias, float* __restrict__ out) {
    __shared__ __align__(1024) char smem[52224];   // 24 rows * 2176B, linear in task

    int n = blockIdx.x;
    int xcd = n & 7, local = n >> 3;
    int dt = local & 15;
    int cmb = (local >> 4) | (xcd << 4);
    int ht = cmb & 15, wt = (cmb >> 4) & 1, b = cmb >> 5;

    int tid = threadIdx.x;
    int lane = tid & 63, wid = tid >> 6;
    int nlo = lane & 31, kh = lane >> 5;

    // A-fragment prefetch of r=0 (independent of staging, overlaps DMA)
    const uint4* kfb = kf2 + (size_t)b * 6912 + lane;
    bf16x8 aCur[4], aNxt[4];
    #pragma unroll
    for (int fi = 0; fi < 4; ++fi)
        aCur[fi] = *(const bf16x8*)(kfb + fi * 64);

    // ---- prologue DMA: 3264 16B chunks, LDS dest linear = task*16
    const char* xtb = (const char*)xt + (size_t)b * 9478656
                    + ((size_t)(dt * 2) * 66 + ht * 4) * XT_ROW_BYTES + wt * 2048;
    #pragma unroll
    for (int it = 0; it < 13; ++it) {
        int task = tid + it * 256;
        if (task < 3264) {
            int row  = task / 136;             // 0..23 = zz*6+yy
            int cidx = task - row * 136;       // 0..135 (xp*4 + slot)
            int zz = row / 6, yy = row - zz * 6;
            const char* gp = xtb + (zz * 66 + yy) * XT_ROW_BYTES + cidx * 16;
            __builtin_amdgcn_global_load_lds(
                (const __attribute__((address_space(1))) void*)gp,
                (__attribute__((address_space(3))) void*)(smem + task * 16),
                16, 0, 0);
        }
    }

    // per-wave tile: 2 M-tiles (o 0-31/32-63) x 2 N-tiles (rows ys, ys+1)
    int z = wid >> 1;
    int ys = (wid & 1) << 1;

    int Badr[2][3];
    #pragma unroll
    for (int s = 0; s < 2; ++s)
        #pragma unroll
        for (int k3 = 0; k3 < 3; ++k3) {
            int xl = nlo + k3;
            int pos = (s * 2 + kh) ^ ((xl >> 1) & 3);
            Badr[s][k3] = (z * 6 + ys) * XROW + xl * 64 + (pos << 4);
        }

    f32x16 acc[2][2];
    #pragma unroll
    for (int mt = 0; mt < 2; ++mt)
        #pragma unroll
        for (int nt = 0; nt < 2; ++nt)
            #pragma unroll
            for (int e = 0; e < 16; ++e) acc[mt][nt][e] = 0.f;

    __syncthreads();   // the ONLY barrier (drains the DMA via vmcnt)

    #pragma unroll
    for (int r = 0; r < 27; ++r) {
        const int i3 = r / 9, j3 = (r / 3) % 3, k3 = r % 3;
        if (r < 26) {
            #pragma unroll
            for (int fi = 0; fi < 4; ++fi)
                aNxt[fi] = *(const bf16x8*)(kfb + ((r + 1) * 4 + fi) * 64);
        }
        #pragma unroll
        for (int s = 0; s < 2; ++s) {
            #pragma unroll
            for (int nt = 0; nt < 2; ++nt) {
                bf16x8 bb = *(const bf16x8*)(smem + (i3 * 6 + j3 + nt) * XROW + Badr[s][k3]);
                acc[0][nt] = __builtin_amdgcn_mfma_f32_32x32x16_bf16(aCur[s * 2 + 0], bb, acc[0][nt], 0, 0, 0);
                acc[1][nt] = __builtin_amdgcn_mfma_f32_32x32x16_bf16(aCur[s * 2 + 1], bb, acc[1][nt], 0, 0, 0);
            }
        }
        if (r < 26) {
            #pragma unroll
            for (int fi = 0; fi < 4; ++fi) aCur[fi] = aNxt[fi];
        }
    }

    // epilogue: D col = lane&31 (w), row = (reg&3)+8*(reg>>2)+4*kh (cout offset)
    int d = dt * 2 + z, w = wt * 32 + nlo;
    #pragma unroll
    for (int mt = 0; mt < 2; ++mt) {
        #pragma unroll
        for (int nt = 0; nt < 2; ++nt) {
            int h = ht * 4 + ys + nt;
            size_t sp = (((size_t)d) * 64 + h) * 64 + w;
            #pragma unroll
            for (int reg = 0; reg < 16; ++reg) {
                int o = mt * 32 + (reg & 3) + 8 * (reg >> 2) + 4 * kh;
                out[(((size_t)(b * 64 + o)) << 17) + sp] = acc[mt][nt][reg] + bias[o];
            }
        }
    }
}

// ---- fallback conv (previous best): used only if workspace is too small for xt.
__global__ __launch_bounds__(256, 2) void conv_fused_fb(
    const float* __restrict__ x, const uint4* __restrict__ kf2,
    const float* __restrict__ bias, float* __restrict__ out) {
    __shared__ __align__(1024) char smem[52224];

    int n = blockIdx.x;
    int xcd = n & 7, local = n >> 3;
    int dt = local & 15;
    int cmb = (local >> 4) | (xcd << 4);
    int ht = cmb & 15, wt = (cmb >> 4) & 1, b = cmb >> 5;

    int tid = threadIdx.x;
    int lane = tid & 63, wid = tid >> 6;
    int nlo = lane & 31, kh = lane >> 5;

    for (int task = tid; task < 3264; task += 256) {
        int row = task / 136;
        int chunk = task - row * 136;
        int q = chunk & 3, xp = chunk >> 2;
        int z = row / 6, yy = row - z * 6;
        int gd = dt * 2 + z - 1, gh = ht * 4 + yy - 1, gw = wt * 32 + xp - 1;
        uint4 v = make_uint4(0u, 0u, 0u, 0u);
        if ((unsigned)gd < 32u && (unsigned)gh < 64u && (unsigned)gw < 64u) {
            const float* xb = x + (((size_t)(b * 32 + q * 8) * 32 + gd) * 64 + gh) * 64 + gw;
            unsigned short us[8];
            #pragma unroll
            for (int j = 0; j < 8; ++j)
                us[j] = f2bf(xb[(size_t)j * 131072]);
            v.x = us[0] | ((unsigned)us[1] << 16);
            v.y = us[2] | ((unsigned)us[3] << 16);
            v.z = us[4] | ((unsigned)us[5] << 16);
            v.w = us[6] | ((unsigned)us[7] << 16);
        }
        int pos = q ^ ((xp >> 1) & 3);
        *(uint4*)(smem + row * XROW + xp * 64 + (pos << 4)) = v;
    }

    int z = wid >> 1;
    int ys = (wid & 1) << 1;

    int Badr[2][3];
    #pragma unroll
    for (int s = 0; s < 2; ++s)
        #pragma unroll
        for (int k3 = 0; k3 < 3; ++k3) {
            int xl = nlo + k3;
            int pos = (s * 2 + kh) ^ ((xl >> 1) & 3);
            Badr[s][k3] = (z * 6 + ys) * XROW + xl * 64 + (pos << 4);
        }

    const uint4* kfb = kf2 + (size_t)b * 6912 + lane;

    bf16x8 aCur[4], aNxt[4];
    #pragma unroll
    for (int fi = 0; fi < 4; ++fi)
        aCur[fi] = *(const bf16x8*)(kfb + fi * 64);

    f32x16 acc[2][2];
    #pragma unroll
    for (int mt = 0; mt < 2; ++mt)
        #pragma unroll
        for (int nt = 0; nt < 2; ++nt)
            #pragma unroll
            for (int e = 0; e < 16; ++e) acc[mt][nt][e] = 0.f;

    __syncthreads();

    #pragma unroll
    for (int r = 0; r < 27; ++r) {
        const int i3 = r / 9, j3 = (r / 3) % 3, k3 = r % 3;
        if (r < 26) {
            #pragma unroll
            for (int fi = 0; fi < 4; ++fi)
                aNxt[fi] = *(const bf16x8*)(kfb + ((r + 1) * 4 + fi) * 64);
        }
        #pragma unroll
        for (int s = 0; s < 2; ++s) {
            #pragma unroll
            for (int nt = 0; nt < 2; ++nt) {
                bf16x8 bb = *(const bf16x8*)(smem + (i3 * 6 + j3 + nt) * XROW + Badr[s][k3]);
                acc[0][nt] = __builtin_amdgcn_mfma_f32_32x32x16_bf16(aCur[s * 2 + 0], bb, acc[0][nt], 0, 0, 0);
                acc[1][nt] = __builtin_amdgcn_mfma_f32_32x32x16_bf16(aCur[s * 2 + 1], bb, acc[1][nt], 0, 0, 0);
            }
        }
        if (r < 26) {
            #pragma unroll
            for (int fi = 0; fi < 4; ++fi) aCur[fi] = aNxt[fi];
        }
    }

    int d = dt * 2 + z, w = wt * 32 + nlo;
    #pragma unroll
    for (int mt = 0; mt < 2; ++mt) {
        #pragma unroll
        for (int nt = 0; nt < 2; ++nt) {
            int h = ht * 4 + ys + nt;
            size_t sp = (((size_t)d) * 64 + h) * 64 + w;
            #pragma unroll
            for (int reg = 0; reg < 16; ++reg) {
                int o = mt * 32 + (reg & 3) + 8 * (reg >> 2) + 4 * kh;
                out[(((size_t)(b * 64 + o)) << 17) + sp] = acc[mt][nt][reg] + bias[o];
            }
        }
    }
}

extern "C" void kernel_launch(void* const* d_in, const int* in_sizes, int n_in,
                              void* d_out, int out_size, void* d_ws, size_t ws_size,
                              hipStream_t stream) {
    const float* x        = (const float*)d_in[0];
    const float* stencils = (const float*)d_in[1];
    const float* weight   = (const float*)d_in[2];
    const float* bias     = (const float*)d_in[3];
    float* out = (float*)d_out;

    uint4* kf2 = (uint4*)d_ws;

    if (ws_size >= (size_t)WS_NEED) {
        uint4* xt = (uint4*)((char*)d_ws + KF2_BYTES);
        prep<<<XT_ROWS + 108, 256, 0, stream>>>(x, stencils, weight, kf2, xt, XT_ROWS);
        conv_fused<<<2048, 256, 0, stream>>>(xt, kf2, bias, out);
    } else {
        prep<<<108, 256, 0, stream>>>(x, stencils, weight, kf2, kf2, 0);
        conv_fused_fb<<<2048, 256, 0, stream>>>(x, kf2, bias, out);
    }
}

// Round 2
// 238.318 us; speedup vs baseline: 1.0504x; 1.0339x over previous
//
#include <hip/hip_runtime.h>

typedef short bf16x8 __attribute__((ext_vector_type(8)));
typedef float f32x16 __attribute__((ext_vector_type(16)));

#define XROW 2176              // 34 xp * 64B per (z,y) LDS row
#define KF2_BYTES 442368       // 27648 * 16
#define XT_ROWS 8976           // 4b * 34pd * 66ph
#define XT_ROW_BYTES 4224      // 66 pw * 64B
#define XT_BYTES 37914624      // 8976 * 4224
#define WS_NEED (KF2_BYTES + XT_BYTES)
#define ABASE 52224            // A dbuf starts after x-tile in LDS
#define AGRP 12288             // 3 r * 4096 B per group

__device__ __forceinline__ unsigned short f2bf(float f) {
    unsigned u = __float_as_uint(f);
    return (unsigned short)((u + 0x7FFFu + ((u >> 16) & 1u)) >> 16);
}

// ---- prep: blocks [0,nxt) build the padded/swizzled bf16 xt tensor;
//            blocks [nxt, nxt+108) build keff (A-fragment order).
// xt layout: row n = (b*34 + pd)*66 + ph holds 66 points (pw) of 64B each.
// Halo rows/points zero-filled so conv needs NO bounds checks.
__global__ __launch_bounds__(256) void prep(const float* __restrict__ x,
                                            const float* __restrict__ stencils,
                                            const float* __restrict__ weight,
                                            uint4* __restrict__ kf2,
                                            uint4* __restrict__ xt,
                                            int nxt) {
    int tid = threadIdx.x;
    int blk = blockIdx.x;

    if (blk >= nxt) {
        // ---- keff: kf2[b][r][fi][lane]; lane chunk = keff[o][c..c+7],
        // o = (lane&31)+32*mt, c = s*16+(lane>>5)*8, fi = s*2+mt.
        int i = (blk - nxt) * 256 + tid;
        if (i >= 27648) return;
        int lane = i & 63;
        int mt = (i >> 6) & 1;
        int s  = (i >> 7) & 1;
        int br = i >> 8;
        int r = br % 27, b = br / 27;
        int o  = (lane & 31) + 32 * mt;
        int cb = s * 16 + (lane >> 5) * 8;
        float st[8];
        #pragma unroll
        for (int t = 0; t < 8; ++t) st[t] = stencils[((size_t)b * 8 + t) * 27 + r];
        unsigned short us[8];
        #pragma unroll
        for (int j = 0; j < 8; ++j) {
            const float* wp = weight + ((size_t)o * 32 + cb + j) * 8;
            float acc = 0.f;
            #pragma unroll
            for (int t = 0; t < 8; ++t) acc += wp[t] * st[t];
            us[j] = f2bf(acc);
        }
        uint4 v;
        v.x = us[0] | ((unsigned)us[1] << 16);
        v.y = us[2] | ((unsigned)us[3] << 16);
        v.z = us[4] | ((unsigned)us[5] << 16);
        v.w = us[6] | ((unsigned)us[7] << 16);
        kf2[i] = v;
        return;
    }

    // ---- xt row
    int n = blk;
    int ph = n % 66;
    int t2 = n / 66;
    int pd = t2 % 34, b = t2 / 34;
    uint4* rowp = xt + (size_t)n * 264;          // 66 pts * 4 uint4
    int d = pd - 1, h = ph - 1;

    if ((unsigned)d >= 32u || (unsigned)h >= 64u) {
        for (int i = tid; i < 264; i += 256) rowp[i] = make_uint4(0u, 0u, 0u, 0u);
        return;
    }

    // interior: wave q reads channels [8q,8q+8) fully coalesced (256B/instr).
    // x is read exactly once -> nontemporal (don't pollute L2, keep kf2/xt hot).
    int q = tid >> 6, w = tid & 63;
    const float* xb = x + (((size_t)(b * 32 + q * 8) * 32 + d) * 64 + h) * 64 + w;
    unsigned short us[8];
    #pragma unroll
    for (int j = 0; j < 8; ++j) us[j] = f2bf(__builtin_nontemporal_load(xb + (size_t)j * 131072));
    uint4 v;
    v.x = us[0] | ((unsigned)us[1] << 16);
    v.y = us[2] | ((unsigned)us[3] << 16);
    v.z = us[4] | ((unsigned)us[5] << 16);
    v.w = us[6] | ((unsigned)us[7] << 16);
    int pw = w + 1;
    int pos = q ^ ((pw >> 1) & 3);
    rowp[pw * 4 + pos] = v;
    if (tid < 4)      rowp[tid]       = make_uint4(0u, 0u, 0u, 0u);
    else if (tid < 8) rowp[256 + tid] = make_uint4(0u, 0u, 0u, 0u);
}

// ---- conv: block = 64 couts x (2d x 4h x 32w).
// B (x tile): pure DMA prologue, 13 global_load_lds dwordx4 per thread.
// A (keff): cooperatively staged through LDS, double-buffered in groups of
// 3 r (12 KB/group, 3 DMA chunks/thread) -> 4x less L2 A-traffic than the
// previous per-wave register stream, and one barrier per group (9 total).
__global__ __launch_bounds__(256, 2) void conv_fused(
    const uint4* __restrict__ xt, const uint4* __restrict__ kf2,
    const float* __restrict__ bias, float* __restrict__ out) {
    __shared__ __align__(1024) char smem[76800];   // [0,52224) x-tile; [52224,76800) A dbuf

    int n = blockIdx.x;
    int xcd = n & 7, local = n >> 3;
    int dt = local & 15;
    int cmb = (local >> 4) | (xcd << 4);
    int ht = cmb & 15, wt = (cmb >> 4) & 1, b = cmb >> 5;

    int tid = threadIdx.x;
    int lane = tid & 63, wid = tid >> 6;
    int nlo = lane & 31, kh = lane >> 5;

    const char* kfb = (const char*)kf2 + (size_t)b * 110592;   // 27*4096 B

    // ---- prologue DMA: x tile (3264 16B chunks, LDS dest linear = task*16)
    const char* xtb = (const char*)xt + (size_t)b * 9478656
                    + ((size_t)(dt * 2) * 66 + ht * 4) * XT_ROW_BYTES + wt * 2048;
    #pragma unroll
    for (int it = 0; it < 13; ++it) {
        int task = tid + it * 256;
        if (task < 3264) {
            int row  = task / 136;             // 0..23 = zz*6+yy
            int cidx = task - row * 136;       // 0..135
            int zz = row / 6, yy = row - zz * 6;
            const char* gp = xtb + (zz * 66 + yy) * XT_ROW_BYTES + cidx * 16;
            __builtin_amdgcn_global_load_lds(
                (const __attribute__((address_space(1))) void*)gp,
                (__attribute__((address_space(3))) void*)(smem + task * 16),
                16, 0, 0);
        }
    }
    // ---- prologue DMA: A group 0 (12 KB, 3 chunks/thread)
    #pragma unroll
    for (int j = 0; j < 3; ++j) {
        __builtin_amdgcn_global_load_lds(
            (const __attribute__((address_space(1))) void*)(kfb + j * 4096 + tid * 16),
            (__attribute__((address_space(3))) void*)(smem + ABASE + j * 4096 + tid * 16),
            16, 0, 0);
    }

    // per-wave tile: 2 M-tiles (o 0-31/32-63) x 2 N-tiles (rows ys, ys+1)
    int z = wid >> 1;
    int ys = (wid & 1) << 1;

    int Badr[2][3];
    #pragma unroll
    for (int s = 0; s < 2; ++s)
        #pragma unroll
        for (int k3 = 0; k3 < 3; ++k3) {
            int xl = nlo + k3;
            int pos = (s * 2 + kh) ^ ((xl >> 1) & 3);
            Badr[s][k3] = (z * 6 + ys) * XROW + xl * 64 + (pos << 4);
        }

    f32x16 acc[2][2];
    #pragma unroll
    for (int mt = 0; mt < 2; ++mt)
        #pragma unroll
        for (int nt = 0; nt < 2; ++nt)
            #pragma unroll
            for (int e = 0; e < 16; ++e) acc[mt][nt][e] = 0.f;

    __syncthreads();   // drains all prologue DMA (vmcnt) + readiness of group 0

    #pragma unroll
    for (int g = 0; g < 9; ++g) {
        const int buf = g & 1;
        if (g < 8) {   // stage next A group into the other buffer
            const char* src = kfb + (g + 1) * AGRP;
            #pragma unroll
            for (int j = 0; j < 3; ++j) {
                __builtin_amdgcn_global_load_lds(
                    (const __attribute__((address_space(1))) void*)(src + j * 4096 + tid * 16),
                    (__attribute__((address_space(3))) void*)(smem + ABASE + (buf ^ 1) * AGRP + j * 4096 + tid * 16),
                    16, 0, 0);
            }
        }
        #pragma unroll
        for (int j = 0; j < 3; ++j) {
            const int r = g * 3 + j;
            const int i3 = r / 9, j3 = (r / 3) % 3, k3 = r % 3;
            bf16x8 a[4];
            #pragma unroll
            for (int fi = 0; fi < 4; ++fi)
                a[fi] = *(const bf16x8*)(smem + ABASE + buf * AGRP + j * 4096 + fi * 1024 + lane * 16);
            #pragma unroll
            for (int s = 0; s < 2; ++s) {
                #pragma unroll
                for (int nt = 0; nt < 2; ++nt) {
                    bf16x8 bb = *(const bf16x8*)(smem + (i3 * 6 + j3 + nt) * XROW + Badr[s][k3]);
                    acc[0][nt] = __builtin_amdgcn_mfma_f32_32x32x16_bf16(a[s * 2 + 0], bb, acc[0][nt], 0, 0, 0);
                    acc[1][nt] = __builtin_amdgcn_mfma_f32_32x32x16_bf16(a[s * 2 + 1], bb, acc[1][nt], 0, 0, 0);
                }
            }
        }
        if (g < 8) __syncthreads();   // next-A DMA drained (vmcnt0) + reads of buf done
    }

    // epilogue: D col = lane&31 (w), row = (reg&3)+8*(reg>>2)+4*kh (cout offset)
    // out is write-only streaming -> nontemporal stores keep xt/kf2 L2-resident.
    int d = dt * 2 + z, w = wt * 32 + nlo;
    #pragma unroll
    for (int mt = 0; mt < 2; ++mt) {
        #pragma unroll
        for (int nt = 0; nt < 2; ++nt) {
            int h = ht * 4 + ys + nt;
            size_t sp = (((size_t)d) * 64 + h) * 64 + w;
            #pragma unroll
            for (int reg = 0; reg < 16; ++reg) {
                int o = mt * 32 + (reg & 3) + 8 * (reg >> 2) + 4 * kh;
                __builtin_nontemporal_store(acc[mt][nt][reg] + bias[o],
                                            &out[(((size_t)(b * 64 + o)) << 17) + sp]);
            }
        }
    }
}

// ---- fallback conv (previous best): used only if workspace is too small for xt.
__global__ __launch_bounds__(256, 2) void conv_fused_fb(
    const float* __restrict__ x, const uint4* __restrict__ kf2,
    const float* __restrict__ bias, float* __restrict__ out) {
    __shared__ __align__(1024) char smem[52224];

    int n = blockIdx.x;
    int xcd = n & 7, local = n >> 3;
    int dt = local & 15;
    int cmb = (local >> 4) | (xcd << 4);
    int ht = cmb & 15, wt = (cmb >> 4) & 1, b = cmb >> 5;

    int tid = threadIdx.x;
    int lane = tid & 63, wid = tid >> 6;
    int nlo = lane & 31, kh = lane >> 5;

    for (int task = tid; task < 3264; task += 256) {
        int row = task / 136;
        int chunk = task - row * 136;
        int q = chunk & 3, xp = chunk >> 2;
        int z = row / 6, yy = row - z * 6;
        int gd = dt * 2 + z - 1, gh = ht * 4 + yy - 1, gw = wt * 32 + xp - 1;
        uint4 v = make_uint4(0u, 0u, 0u, 0u);
        if ((unsigned)gd < 32u && (unsigned)gh < 64u && (unsigned)gw < 64u) {
            const float* xb = x + (((size_t)(b * 32 + q * 8) * 32 + gd) * 64 + gh) * 64 + gw;
            unsigned short us[8];
            #pragma unroll
            for (int j = 0; j < 8; ++j)
                us[j] = f2bf(xb[(size_t)j * 131072]);
            v.x = us[0] | ((unsigned)us[1] << 16);
            v.y = us[2] | ((unsigned)us[3] << 16);
            v.z = us[4] | ((unsigned)us[5] << 16);
            v.w = us[6] | ((unsigned)us[7] << 16);
        }
        int pos = q ^ ((xp >> 1) & 3);
        *(uint4*)(smem + row * XROW + xp * 64 + (pos << 4)) = v;
    }

    int z = wid >> 1;
    int ys = (wid & 1) << 1;

    int Badr[2][3];
    #pragma unroll
    for (int s = 0; s < 2; ++s)
        #pragma unroll
        for (int k3 = 0; k3 < 3; ++k3) {
            int xl = nlo + k3;
            int pos = (s * 2 + kh) ^ ((xl >> 1) & 3);
            Badr[s][k3] = (z * 6 + ys) * XROW + xl * 64 + (pos << 4);
        }

    const uint4* kfb = kf2 + (size_t)b * 6912 + lane;

    bf16x8 aCur[4], aNxt[4];
    #pragma unroll
    for (int fi = 0; fi < 4; ++fi)
        aCur[fi] = *(const bf16x8*)(kfb + fi * 64);

    f32x16 acc[2][2];
    #pragma unroll
    for (int mt = 0; mt < 2; ++mt)
        #pragma unroll
        for (int nt = 0; nt < 2; ++nt)
            #pragma unroll
            for (int e = 0; e < 16; ++e) acc[mt][nt][e] = 0.f;

    __syncthreads();

    #pragma unroll
    for (int r = 0; r < 27; ++r) {
        const int i3 = r / 9, j3 = (r / 3) % 3, k3 = r % 3;
        if (r < 26) {
            #pragma unroll
            for (int fi = 0; fi < 4; ++fi)
                aNxt[fi] = *(const bf16x8*)(kfb + ((r + 1) * 4 + fi) * 64);
        }
        #pragma unroll
        for (int s = 0; s < 2; ++s) {
            #pragma unroll
            for (int nt = 0; nt < 2; ++nt) {
                bf16x8 bb = *(const bf16x8*)(smem + (i3 * 6 + j3 + nt) * XROW + Badr[s][k3]);
                acc[0][nt] = __builtin_amdgcn_mfma_f32_32x32x16_bf16(aCur[s * 2 + 0], bb, acc[0][nt], 0, 0, 0);
                acc[1][nt] = __builtin_amdgcn_mfma_f32_32x32x16_bf16(aCur[s * 2 + 1], bb, acc[1][nt], 0, 0, 0);
            }
        }
        if (r < 26) {
            #pragma unroll
            for (int fi = 0; fi < 4; ++fi) aCur[fi] = aNxt[fi];
        }
    }

    int d = dt * 2 + z, w = wt * 32 + nlo;
    #pragma unroll
    for (int mt = 0; mt < 2; ++mt) {
        #pragma unroll
        for (int nt = 0; nt < 2; ++nt) {
            int h = ht * 4 + ys + nt;
            size_t sp = (((size_t)d) * 64 + h) * 64 + w;
            #pragma unroll
            for (int reg = 0; reg < 16; ++reg) {
                int o = mt * 32 + (reg & 3) + 8 * (reg >> 2) + 4 * kh;
                out[(((size_t)(b * 64 + o)) << 17) + sp] = acc[mt][nt][reg] + bias[o];
            }
        }
    }
}

extern "C" void kernel_launch(void* const* d_in, const int* in_sizes, int n_in,
                              void* d_out, int out_size, void* d_ws, size_t ws_size,
                              hipStream_t stream) {
    const float* x        = (const float*)d_in[0];
    const float* stencils = (const float*)d_in[1];
    const float* weight   = (const float*)d_in[2];
    const float* bias     = (const float*)d_in[3];
    float* out = (float*)d_out;

    uint4* kf2 = (uint4*)d_ws;

    if (ws_size >= (size_t)WS_NEED) {
        uint4* xt = (uint4*)((char*)d_ws + KF2_BYTES);
        prep<<<XT_ROWS + 108, 256, 0, stream>>>(x, stencils, weight, kf2, xt, XT_ROWS);
        conv_fused<<<2048, 256, 0, stream>>>(xt, kf2, bias, out);
    } else {
        prep<<<108, 256, 0, stream>>>(x, stencils, weight, kf2, kf2, 0);
        conv_fused_fb<<<2048, 256, 0, stream>>>(x, kf2, bias, out);
    }
}

// Round 3
// 237.128 us; speedup vs baseline: 1.0557x; 1.0050x over previous
//
#include <hip/hip_runtime.h>

typedef short bf16x8 __attribute__((ext_vector_type(8)));
typedef float f32x16 __attribute__((ext_vector_type(16)));

#define XROW 2176              // 34 xp * 64B per (z,y) LDS row
#define KF2_BYTES 442368       // 27648 * 16
#define XT_ROWS 8976           // 4b * 34pd * 66ph
#define XT_ROW_BYTES 4224      // 66 pw * 64B
#define XT_BYTES 37914624      // 8976 * 4224
#define WS_NEED (KF2_BYTES + XT_BYTES)

__device__ __forceinline__ unsigned short f2bf(float f) {
    unsigned u = __float_as_uint(f);
    return (unsigned short)((u + 0x7FFFu + ((u >> 16) & 1u)) >> 16);
}

// ---- prep: blocks [0,nxt) build the padded/swizzled bf16 xt tensor;
//            blocks [nxt, nxt+108) build keff (A-fragment order).
// xt layout: row n = (b*34 + pd)*66 + ph holds 66 points (pw) of 64B each.
// Halo rows/points zero-filled so conv needs NO bounds checks.
__global__ __launch_bounds__(256) void prep(const float* __restrict__ x,
                                            const float* __restrict__ stencils,
                                            const float* __restrict__ weight,
                                            uint4* __restrict__ kf2,
                                            uint4* __restrict__ xt,
                                            int nxt) {
    int tid = threadIdx.x;
    int blk = blockIdx.x;

    if (blk >= nxt) {
        // ---- keff: kf2[b][r][fi][lane]; lane chunk = keff[o][c..c+7],
        // o = (lane&31)+32*mt, c = s*16+(lane>>5)*8, fi = s*2+mt.
        int i = (blk - nxt) * 256 + tid;
        if (i >= 27648) return;
        int lane = i & 63;
        int mt = (i >> 6) & 1;
        int s  = (i >> 7) & 1;
        int br = i >> 8;
        int r = br % 27, b = br / 27;
        int o  = (lane & 31) + 32 * mt;
        int cb = s * 16 + (lane >> 5) * 8;
        float st[8];
        #pragma unroll
        for (int t = 0; t < 8; ++t) st[t] = stencils[((size_t)b * 8 + t) * 27 + r];
        unsigned short us[8];
        #pragma unroll
        for (int j = 0; j < 8; ++j) {
            const float* wp = weight + ((size_t)o * 32 + cb + j) * 8;
            float acc = 0.f;
            #pragma unroll
            for (int t = 0; t < 8; ++t) acc += wp[t] * st[t];
            us[j] = f2bf(acc);
        }
        uint4 v;
        v.x = us[0] | ((unsigned)us[1] << 16);
        v.y = us[2] | ((unsigned)us[3] << 16);
        v.z = us[4] | ((unsigned)us[5] << 16);
        v.w = us[6] | ((unsigned)us[7] << 16);
        kf2[i] = v;
        return;
    }

    // ---- xt row
    int n = blk;
    int ph = n % 66;
    int t2 = n / 66;
    int pd = t2 % 34, b = t2 / 34;
    uint4* rowp = xt + (size_t)n * 264;          // 66 pts * 4 uint4
    int d = pd - 1, h = ph - 1;

    if ((unsigned)d >= 32u || (unsigned)h >= 64u) {
        for (int i = tid; i < 264; i += 256) rowp[i] = make_uint4(0u, 0u, 0u, 0u);
        return;
    }

    // interior: wave q reads channels [8q,8q+8) fully coalesced (256B/instr).
    int q = tid >> 6, w = tid & 63;
    const float* xb = x + (((size_t)(b * 32 + q * 8) * 32 + d) * 64 + h) * 64 + w;
    unsigned short us[8];
    #pragma unroll
    for (int j = 0; j < 8; ++j) us[j] = f2bf(__builtin_nontemporal_load(xb + (size_t)j * 131072));
    uint4 v;
    v.x = us[0] | ((unsigned)us[1] << 16);
    v.y = us[2] | ((unsigned)us[3] << 16);
    v.z = us[4] | ((unsigned)us[5] << 16);
    v.w = us[6] | ((unsigned)us[7] << 16);
    int pw = w + 1;
    int pos = q ^ ((pw >> 1) & 3);
    rowp[pw * 4 + pos] = v;
    if (tid < 4)      rowp[tid]       = make_uint4(0u, 0u, 0u, 0u);
    else if (tid < 8) rowp[256 + tid] = make_uint4(0u, 0u, 0u, 0u);
}

// ---- conv: block = 64 couts x (4d x 4h x 32w), grid 1024, one wave per z.
// Wide wave tile (mt=2, nt=4): per r per wave = 4 A-loads + 8 ds_read_b128 +
// 16 MFMA -> 0.75 LDS reads/MFMA (was 1.0) and a 16-MFMA ILP run per r.
// A (keff) streamed global->reg, 1-deep prefetch (L2-resident per XCD).
// Single barrier. Halo amplification 2.39x (was 3.19x).
__global__ __launch_bounds__(256, 2) void conv_fused(
    const uint4* __restrict__ xt, const uint4* __restrict__ kf2,
    const float* __restrict__ bias, float* __restrict__ out) {
    __shared__ __align__(1024) char smem[78336];   // 36 rows (6z x 6y) * 2176B

    int n = blockIdx.x;
    int xcd = n & 7, local = n >> 3;   // per-XCD: one (b,wt) slab -> L2 locality
    int dt = local & 7, ht = local >> 3;
    int wt = xcd & 1, b = xcd >> 1;

    int tid = threadIdx.x;
    int lane = tid & 63, wid = tid >> 6;
    int nlo = lane & 31, kh = lane >> 5;

    // A stream base: kf2 byte layout = b*110592 + r*4096 + fi*1024 + lane*16
    const char* kfb = (const char*)kf2 + (size_t)b * 110592 + lane * 16;

    // A prefetch r=0 (independent of staging, overlaps DMA)
    bf16x8 aCur[4], aNxt[4];
    #pragma unroll
    for (int fi = 0; fi < 4; ++fi)
        aCur[fi] = *(const bf16x8*)(kfb + fi * 1024);

    // ---- prologue DMA: x tile, 4896 16B chunks, LDS dest linear = task*16
    const char* xtb = (const char*)xt + (size_t)b * 9478656
                    + ((size_t)(dt * 4) * 66 + ht * 4) * XT_ROW_BYTES + wt * 2048;
    #pragma unroll
    for (int it = 0; it < 20; ++it) {
        int task = tid + it * 256;
        if (task < 4896) {
            int row  = task / 136;             // 0..35 = zz*6+yy
            int cidx = task - row * 136;       // 0..135
            int zz = row / 6, yy = row - zz * 6;
            const char* gp = xtb + (zz * 66 + yy) * XT_ROW_BYTES + cidx * 16;
            __builtin_amdgcn_global_load_lds(
                (const __attribute__((address_space(1))) void*)gp,
                (__attribute__((address_space(3))) void*)(smem + task * 16),
                16, 0, 0);
        }
    }

    int z = wid;   // wave owns output z-slice dt*4 + z, all 4 h-rows

    int Badr[2][3];
    #pragma unroll
    for (int s = 0; s < 2; ++s)
        #pragma unroll
        for (int k3 = 0; k3 < 3; ++k3) {
            int xl = nlo + k3;
            int pos = (s * 2 + kh) ^ ((xl >> 1) & 3);
            Badr[s][k3] = xl * 64 + (pos << 4);
        }

    f32x16 acc[2][4];
    #pragma unroll
    for (int mt = 0; mt < 2; ++mt)
        #pragma unroll
        for (int nt = 0; nt < 4; ++nt)
            #pragma unroll
            for (int e = 0; e < 16; ++e) acc[mt][nt][e] = 0.f;

    __syncthreads();   // the ONLY barrier (drains the DMA via vmcnt)

    #pragma unroll
    for (int r = 0; r < 27; ++r) {
        const int i3 = r / 9, j3 = (r / 3) % 3, k3 = r % 3;
        if (r < 26) {
            #pragma unroll
            for (int fi = 0; fi < 4; ++fi)
                aNxt[fi] = *(const bf16x8*)(kfb + (r + 1) * 4096 + fi * 1024);
        }
        #pragma unroll
        for (int s = 0; s < 2; ++s) {
            #pragma unroll
            for (int nt = 0; nt < 4; ++nt) {
                bf16x8 bb = *(const bf16x8*)(smem + ((z + i3) * 6 + j3 + nt) * XROW + Badr[s][k3]);
                acc[0][nt] = __builtin_amdgcn_mfma_f32_32x32x16_bf16(aCur[s * 2 + 0], bb, acc[0][nt], 0, 0, 0);
                acc[1][nt] = __builtin_amdgcn_mfma_f32_32x32x16_bf16(aCur[s * 2 + 1], bb, acc[1][nt], 0, 0, 0);
            }
        }
        if (r < 26) {
            #pragma unroll
            for (int fi = 0; fi < 4; ++fi) aCur[fi] = aNxt[fi];
        }
    }

    // epilogue: D col = lane&31 (w), row = (reg&3)+8*(reg>>2)+4*kh (cout offset)
    int d = dt * 4 + z, w = wt * 32 + nlo;
    #pragma unroll
    for (int mt = 0; mt < 2; ++mt) {
        #pragma unroll
        for (int nt = 0; nt < 4; ++nt) {
            int h = ht * 4 + nt;
            size_t sp = (((size_t)d) * 64 + h) * 64 + w;
            #pragma unroll
            for (int reg = 0; reg < 16; ++reg) {
                int o = mt * 32 + (reg & 3) + 8 * (reg >> 2) + 4 * kh;
                __builtin_nontemporal_store(acc[mt][nt][reg] + bias[o],
                                            &out[(((size_t)(b * 64 + o)) << 17) + sp]);
            }
        }
    }
}

// ---- fallback conv (previous best): used only if workspace is too small for xt.
__global__ __launch_bounds__(256, 2) void conv_fused_fb(
    const float* __restrict__ x, const uint4* __restrict__ kf2,
    const float* __restrict__ bias, float* __restrict__ out) {
    __shared__ __align__(1024) char smem[52224];

    int n = blockIdx.x;
    int xcd = n & 7, local = n >> 3;
    int dt = local & 15;
    int cmb = (local >> 4) | (xcd << 4);
    int ht = cmb & 15, wt = (cmb >> 4) & 1, b = cmb >> 5;

    int tid = threadIdx.x;
    int lane = tid & 63, wid = tid >> 6;
    int nlo = lane & 31, kh = lane >> 5;

    for (int task = tid; task < 3264; task += 256) {
        int row = task / 136;
        int chunk = task - row * 136;
        int q = chunk & 3, xp = chunk >> 2;
        int z = row / 6, yy = row - z * 6;
        int gd = dt * 2 + z - 1, gh = ht * 4 + yy - 1, gw = wt * 32 + xp - 1;
        uint4 v = make_uint4(0u, 0u, 0u, 0u);
        if ((unsigned)gd < 32u && (unsigned)gh < 64u && (unsigned)gw < 64u) {
            const float* xb = x + (((size_t)(b * 32 + q * 8) * 32 + gd) * 64 + gh) * 64 + gw;
            unsigned short us[8];
            #pragma unroll
            for (int j = 0; j < 8; ++j)
                us[j] = f2bf(xb[(size_t)j * 131072]);
            v.x = us[0] | ((unsigned)us[1] << 16);
            v.y = us[2] | ((unsigned)us[3] << 16);
            v.z = us[4] | ((unsigned)us[5] << 16);
            v.w = us[6] | ((unsigned)us[7] << 16);
        }
        int pos = q ^ ((xp >> 1) & 3);
        *(uint4*)(smem + row * XROW + xp * 64 + (pos << 4)) = v;
    }

    int z = wid >> 1;
    int ys = (wid & 1) << 1;

    int Badr[2][3];
    #pragma unroll
    for (int s = 0; s < 2; ++s)
        #pragma unroll
        for (int k3 = 0; k3 < 3; ++k3) {
            int xl = nlo + k3;
            int pos = (s * 2 + kh) ^ ((xl >> 1) & 3);
            Badr[s][k3] = (z * 6 + ys) * XROW + xl * 64 + (pos << 4);
        }

    const uint4* kfb = kf2 + (size_t)b * 6912 + lane;

    bf16x8 aCur[4], aNxt[4];
    #pragma unroll
    for (int fi = 0; fi < 4; ++fi)
        aCur[fi] = *(const bf16x8*)(kfb + fi * 64);

    f32x16 acc[2][2];
    #pragma unroll
    for (int mt = 0; mt < 2; ++mt)
        #pragma unroll
        for (int nt = 0; nt < 2; ++nt)
            #pragma unroll
            for (int e = 0; e < 16; ++e) acc[mt][nt][e] = 0.f;

    __syncthreads();

    #pragma unroll
    for (int r = 0; r < 27; ++r) {
        const int i3 = r / 9, j3 = (r / 3) % 3, k3 = r % 3;
        if (r < 26) {
            #pragma unroll
            for (int fi = 0; fi < 4; ++fi)
                aNxt[fi] = *(const bf16x8*)(kfb + ((r + 1) * 4 + fi) * 64);
        }
        #pragma unroll
        for (int s = 0; s < 2; ++s) {
            #pragma unroll
            for (int nt = 0; nt < 2; ++nt) {
                bf16x8 bb = *(const bf16x8*)(smem + (i3 * 6 + j3 + nt) * XROW + Badr[s][k3]);
                acc[0][nt] = __builtin_amdgcn_mfma_f32_32x32x16_bf16(aCur[s * 2 + 0], bb, acc[0][nt], 0, 0, 0);
                acc[1][nt] = __builtin_amdgcn_mfma_f32_32x32x16_bf16(aCur[s * 2 + 1], bb, acc[1][nt], 0, 0, 0);
            }
        }
        if (r < 26) {
            #pragma unroll
            for (int fi = 0; fi < 4; ++fi) aCur[fi] = aNxt[fi];
        }
    }

    int d = dt * 2 + z, w = wt * 32 + nlo;
    #pragma unroll
    for (int mt = 0; mt < 2; ++mt) {
        #pragma unroll
        for (int nt = 0; nt < 2; ++nt) {
            int h = ht * 4 + ys + nt;
            size_t sp = (((size_t)d) * 64 + h) * 64 + w;
            #pragma unroll
            for (int reg = 0; reg < 16; ++reg) {
                int o = mt * 32 + (reg & 3) + 8 * (reg >> 2) + 4 * kh;
                out[(((size_t)(b * 64 + o)) << 17) + sp] = acc[mt][nt][reg] + bias[o];
            }
        }
    }
}

extern "C" void kernel_launch(void* const* d_in, const int* in_sizes, int n_in,
                              void* d_out, int out_size, void* d_ws, size_t ws_size,
                              hipStream_t stream) {
    const float* x        = (const float*)d_in[0];
    const float* stencils = (const float*)d_in[1];
    const float* weight   = (const float*)d_in[2];
    const float* bias     = (const float*)d_in[3];
    float* out = (float*)d_out;

    uint4* kf2 = (uint4*)d_ws;

    if (ws_size >= (size_t)WS_NEED) {
        uint4* xt = (uint4*)((char*)d_ws + KF2_BYTES);
        prep<<<XT_ROWS + 108, 256, 0, stream>>>(x, stencils, weight, kf2, xt, XT_ROWS);
        conv_fused<<<1024, 256, 0, stream>>>(xt, kf2, bias, out);
    } else {
        prep<<<108, 256, 0, stream>>>(x, stencils, weight, kf2, kf2, 0);
        conv_fused_fb<<<2048, 256, 0, stream>>>(x, kf2, bias, out);
    }
}